// Round 1
// 11846.504 us; speedup vs baseline: 1.6006x; 1.6006x over previous
//
#include <hip/hip_runtime.h>

typedef unsigned short u16;
typedef unsigned int   u32;
typedef unsigned long long u64;

typedef __attribute__((ext_vector_type(8))) _Float16 half8;
typedef __attribute__((ext_vector_type(4))) float    f32x4;

#define T_STEPS 512

// ---------- helpers ----------
__device__ __forceinline__ f32x4 mfma16(uint4 a, uint4 b, f32x4 c) {
  union { uint4 u; half8 h; } A, B;
  A.u = a; B.u = b;
  return __builtin_amdgcn_mfma_f32_16x16x32_f16(A.h, B.h, c, 0, 0, 0);
}
__device__ __forceinline__ u16 f2h(float f) {
  union { _Float16 h; u16 u; } x; x.h = (_Float16)f; return x.u;
}
__device__ __forceinline__ float h2f(u16 v) {
  union { _Float16 h; u16 u; } x; x.u = v; return (float)x.h;
}
// agent-scope (device-coherent, bypass L1/L2) for cross-workgroup state
__device__ __forceinline__ void sth(u16* p, u16 v) {
  __hip_atomic_store(p, v, __ATOMIC_RELAXED, __HIP_MEMORY_SCOPE_AGENT);
}
__device__ __forceinline__ u64 ld8(const u64* p) {
  return __hip_atomic_load(p, __ATOMIC_RELAXED, __HIP_MEMORY_SCOPE_AGENT);
}
__device__ __forceinline__ float sigm(float x)  { return 1.0f / (1.0f + __expf(-x)); }
__device__ __forceinline__ float tanhx(float x) { return 2.0f / (1.0f + __expf(-2.0f * x)) - 1.0f; }

// load the wave's 16-row A-fragment set (16 uint4) straight from global
__device__ __forceinline__ void frag_load(uint4* af, const u16* buf, int rowoff) {
#pragma unroll
  for (int kc = 0; kc < 16; ++kc) {
    const u64* p = (const u64*)(buf + rowoff + kc * 32);
    u64 lo = ld8(p), hi = ld8(p + 1);
    af[kc].x = (u32)lo; af[kc].y = (u32)(lo >> 32);
    af[kc].z = (u32)hi; af[kc].w = (u32)(hi >> 32);
  }
}
// 16-MFMA matmul: A-frags (regs) x LDS weight slice
__device__ __forceinline__ f32x4 mm(const uint4* af, const uint4* lw, int slice, int lane) {
  f32x4 acc = {0.f, 0.f, 0.f, 0.f};
#pragma unroll
  for (int kc = 0; kc < 16; ++kc)
    acc = mfma16(af[kc], lw[slice * 1024 + kc * 64 + lane], acc);
  return acc;
}

// ---- per-wave dataflow sync (NO compiler agent fences -> no L2 wb/inv ops) ----
// All cross-wg payload traffic is agent-scope (cache-bypassing) loads/stores, so
// manual ordering is sufficient: drain this wave's stores (vmcnt) and LDS writes
// (lgkmcnt), then publish the flag with a relaxed agent store.
__device__ __forceinline__ void wave_signal(u32* slot, u32 epoch) {
  asm volatile("s_waitcnt vmcnt(0) lgkmcnt(0)" ::: "memory");
  if ((threadIdx.x & 63) == 0)
    __hip_atomic_store(slot, epoch, __ATOMIC_RELAXED, __HIP_MEMORY_SCOPE_AGENT);
}
// lane l polls producer-wg l's flag (64B apart); wave proceeds when all 64 reached epoch.
__device__ __forceinline__ void wave_wait(const u32* base, u32 epoch) {
  const u32* p = base + (size_t)(threadIdx.x & 63) * 16;
  while (__hip_atomic_load(p, __ATOMIC_RELAXED, __HIP_MEMORY_SCOPE_AGENT) < epoch) {}
  asm volatile("" ::: "memory");
}

// ---------- prelude 1: pack weights (f32 -> fp16) into MFMA B-fragment lane order ----------
__global__ __launch_bounds__(256) void pack_kernel(const float* __restrict__ w0,
                                                   const float* __restrict__ wsrc,
                                                   u16* __restrict__ wp) {
  int gid = blockIdx.x * 256 + threadIdx.x;  // < 655360
  int w = gid >> 16, c = gid & 65535;
  int jb = c >> 10, kc = (c >> 6) & 15, lane = c & 63;
  int nl = lane & 15, kh = lane >> 4;
  int n = (nl < 8) ? (jb * 8 + nl) : (512 + jb * 8 + nl - 8);
  int k = kc * 32 + kh * 8;
  const float* s;
  if (w == 0)      s = w0 + (size_t)k * 1024 + n;
  else if (w == 1) s = w0 + (size_t)(512 + k) * 1024 + n;
  else             s = wsrc + (size_t)(w - 2) * 524288 + (size_t)k * 1024 + n;
  u32 e[8];
#pragma unroll
  for (int i = 0; i < 8; ++i) e[i] = (u32)f2h(s[(size_t)i * 1024]);
  uint4 v;
  v.x = e[0] | (e[1] << 16); v.y = e[2] | (e[3] << 16);
  v.z = e[4] | (e[5] << 16); v.w = e[6] | (e[7] << 16);
  ((uint4*)wp)[gid] = v;
}

// ---------- prelude 2: XW = x[t] @ W0x, stored PACKED in C-frag layout ----------
__global__ __launch_bounds__(256) void xw_kernel(const float* __restrict__ x,
                                                 const u16* __restrict__ wp,
                                                 u64* __restrict__ xwp) {
  __shared__ uint4 smem[4096];  // 64KB: full x[t] in A-frag layout
  int t = blockIdx.x >> 4, jbg = blockIdx.x & 15;
  int tid = threadIdx.x, lane = tid & 63, wv = tid >> 6;
  const float* src = x + (size_t)t * 64 * 512;
#pragma unroll
  for (int it = 0; it < 16; ++it) {
    int d = tid + it * 256;
    int ln = d & 63, kcL = (d >> 6) & 15, mtL = d >> 10;
    int lm = mtL * 16 + (ln & 15);
    int k8 = kcL * 4 + (ln >> 4);
    const float* p = src + (size_t)lm * 512 + (size_t)k8 * 8;
    float4 a = *(const float4*)p;
    float4 b = *(const float4*)(p + 4);
    uint4 v;
    v.x = (u32)f2h(a.x) | ((u32)f2h(a.y) << 16);
    v.y = (u32)f2h(a.z) | ((u32)f2h(a.w) << 16);
    v.z = (u32)f2h(b.x) | ((u32)f2h(b.y) << 16);
    v.w = (u32)f2h(b.z) | ((u32)f2h(b.w) << 16);
    smem[d] = v;
  }
  __syncthreads();
  int jb = jbg * 4 + wv;
  const uint4* bp = (const uint4*)wp + (size_t)jb * 1024;  // pack 0 = W0x
  f32x4 acc[4] = {{0,0,0,0},{0,0,0,0},{0,0,0,0},{0,0,0,0}};
#pragma unroll
  for (int kc = 0; kc < 16; ++kc) {
    uint4 b = bp[kc * 64 + lane];
#pragma unroll
    for (int m4 = 0; m4 < 4; ++m4)
      acc[m4] = mfma16(smem[(m4 * 16 + kc) * 64 + lane], b, acc[m4]);
  }
#pragma unroll
  for (int m4 = 0; m4 < 4; ++m4) {
    u32 lo = (u32)f2h(acc[m4][0]) | ((u32)f2h(acc[m4][1]) << 16);
    u32 hi = (u32)f2h(acc[m4][2]) | ((u32)f2h(acc[m4][3]) << 16);
    xwp[((size_t)(t * 64 + jb) * 4 + m4) * 64 + lane] = (u64)lo | ((u64)hi << 32);
  }
}

// ---------- prelude 3: fp16 mirror of h_in ----------
__global__ __launch_bounds__(256) void init_hh(const float* __restrict__ h, u16* __restrict__ hh) {
  int i = blockIdx.x * 256 + threadIdx.x;
  if (i < 32768) hh[i] = f2h(h[i]);
}

// ---------- persistent recurrence: per-wave dataflow, zero in-loop __syncthreads ----------
// 128 wgs: jb = wg&63, g = wg>>6 (rows g*32..+32). 4 waves: mt = wid&1, sel = wid>>1.
// Flag channels per group (each 64 slots x 64B): 0+mt: A(s0 tile mt, by sel0-mt),
// 2+2*sel+mt: B(s_{1+sel} tile mt), 6+mt: C(s3&s4 tile mt, by sel0-mt), 8+mt: D(h tile mt).
// Hand-rolled release: vmcnt/lgkm drain + relaxed agent flag store (no buffer_wbl2/inv).
// Intra-wg LDS handoffs (scr_s0/scr_s4) are covered by the same flags (lgkm drained
// before signal); sel1->sel0 mean handoff at D uses one LDS flag.
__global__ __launch_bounds__(256) void recur_kernel(
    const u64* __restrict__ xwp, const float* __restrict__ h_in,
    const u16* __restrict__ wp,
    u16* __restrict__ sh,   // s0..s4 fp16 [5][64][512]
    u16* __restrict__ hh,   // h fp16 [64][512]
    u32* __restrict__ bar,
    float* __restrict__ out) {
  extern __shared__ char smem_raw[];
  uint4* lw     = (uint4*)smem_raw;                 // [9][16][64] uint4 = 147456B
  float* scr_s0 = (float*)(smem_raw + 147456);      // [256] f32
  float* scr_s4 = (float*)(smem_raw + 148480);      // [256]
  float* scr_m1 = (float*)(smem_raw + 149504);      // [256]
  u32*   lflag  = (u32*)(smem_raw + 150528);        // [2]

  const int wg = blockIdx.x;
  const int jb = wg & 63, g = wg >> 6;
  const int rb = g * 32;
  const int tid = threadIdx.x;
  const int lane = tid & 63;
  const int wid = tid >> 6;
  const int mt = wid & 1, sel = wid >> 1;
  const int n = lane & 15, r0 = (lane >> 4) * 4;
  const int rowoff = (rb + mt * 16 + n) * 512 + (lane >> 4) * 8;  // fp16 elems
  const int jj = jb * 8 + (n & 7);                  // owner column (used when n<8)
  const int sbase = (mt * 16 + r0) * 8 + (n & 7);   // scr index, +i*8
  u32* flg = bar + (size_t)g * 10240;               // 10 ch x 64 slots x 16 u32
  const uint4* wp4 = (const uint4*)wp;
  u32* chA = flg + (0 + mt) * 1024;
  u32* chB = flg + (2 + 2 * sel + mt) * 1024;
  u32* chC = flg + (6 + mt) * 1024;
  u32* chD = flg + (8 + mt) * 1024;

  // preload all 9 weight jb-slices into LDS (slice s = pack 1+s)
  for (int idx = tid; idx < 9216; idx += 256) {
    int s = idx >> 10, rem = idx & 1023;
    lw[idx] = wp4[(size_t)(1 + s) * 65536 + (size_t)jb * 1024 + rem];
  }
  if (tid < 2) lflag[tid] = 0;
  __syncthreads();

  float h_reg[4];                // fp32 h for this lane's (rows, jj)
  float mean[4] = {0, 0, 0, 0};
  float s0r[4], s1r[4], s3r[4];
  u64 xv = 0;
  if (sel == 0)  // register-carried XW for t=0
    xv = xwp[((size_t)(0 * 64 + jb) * 4 + (g * 2 + mt)) * 64 + lane];

  for (int t = 0; t < T_STEPS; ++t) {
    const u32 ep = (u32)t + 1;
    uint4 af[16];
    if (sel == 0) {
      // ---------- stage A: s0 = gate(XW[t] + h @ W0h) ----------
      wave_wait(chD, (u32)t);                   // prev step's h tile published
      frag_load(af, hh, rowoff);
      f32x4 acc = mm(af, lw, 0, lane);
      float v[4], part[4];
#pragma unroll
      for (int i = 0; i < 4; ++i) v[i] = acc[i] + h2f((u16)(xv >> (16 * i)));
#pragma unroll
      for (int i = 0; i < 4; ++i) part[i] = __shfl_xor(v[i], 8);
      if (n < 8) {
#pragma unroll
        for (int i = 0; i < 4; ++i) {
          int m = rb + mt * 16 + r0 + i;
          float hp = (t == 0) ? h_in[m * 512 + jj] : h_reg[i];
          float s0 = hp + sigm(v[i]) * (tanhx(part[i]) - hp);
          s0r[i] = s0;
          scr_s0[sbase + i * 8] = s0;
          sth(sh + m * 512 + jj, f2h(s0));
        }
      }
      wave_signal(chA + jb * 16, ep);
      int tn = (t < T_STEPS - 1) ? t + 1 : t;   // real register prefetch of next XW
      xv = xwp[((size_t)(tn * 64 + jb) * 4 + (g * 2 + mt)) * 64 + lane];
    }
    // ---------- stage B: s1 = tanh-step(s0) [sel0], s2 = relu-step(s0) [sel1] ----------
    wave_wait(chA, ep);
    frag_load(af, sh, rowoff);
    {
      f32x4 acc = mm(af, lw, 1 + sel, lane);
      float part[4];
#pragma unroll
      for (int i = 0; i < 4; ++i) part[i] = __shfl_xor(acc[i], 8);
      if (n < 8) {
#pragma unroll
        for (int i = 0; i < 4; ++i) {
          int m = rb + mt * 16 + r0 + i;
          float sp = (sel == 0) ? s0r[i] : scr_s0[sbase + i * 8];
          float hc = (sel == 0) ? tanhx(part[i]) : fmaxf(part[i], 0.f);
          float sn = sp + sigm(acc[i]) * (hc - sp);
          s1r[i] = sn;
          mean[i] = sn;
          sth(sh + (size_t)(1 + sel) * 32768 + m * 512 + jj, f2h(sn));
        }
      }
    }
    wave_signal(chB + jb * 16, ep);
    // ---------- stage C: sel0: s3,s4 from s1 ; sel1: s5,s6 from s2 (mean-only) ----------
    wave_wait(chB, ep);
    frag_load(af, sh + (size_t)(1 + sel) * 32768, rowoff);
    {
      f32x4 a0 = {0, 0, 0, 0}, a1 = {0, 0, 0, 0};
#pragma unroll
      for (int kc = 0; kc < 16; ++kc) {
        uint4 a = af[kc];
        a0 = mfma16(a, lw[(3 + 2 * sel) * 1024 + kc * 64 + lane], a0);
        a1 = mfma16(a, lw[(4 + 2 * sel) * 1024 + kc * 64 + lane], a1);
      }
      float p0[4], p1[4];
#pragma unroll
      for (int i = 0; i < 4; ++i) { p0[i] = __shfl_xor(a0[i], 8); p1[i] = __shfl_xor(a1[i], 8); }
      if (n < 8) {
#pragma unroll
        for (int i = 0; i < 4; ++i) {
          int m = rb + mt * 16 + r0 + i;
          float sp = s1r[i];
          if (sel == 0) {
            float s3 = sp + sigm(a0[i]) * (sigm(p0[i]) - sp);        // step2: sigmoid
            float s4 = sp + sigm(a1[i]) * (p1[i] - sp);              // step3: identity
            mean[i] += s3 + s4;
            s3r[i] = s3;
            scr_s4[sbase + i * 8] = s4;
            sth(sh + (size_t)3 * 32768 + m * 512 + jj, f2h(s3));
            sth(sh + (size_t)4 * 32768 + m * 512 + jj, f2h(s4));
          } else {
            float s5 = sp + sigm(a0[i]) * (tanhx(p0[i]) - sp);       // step4: tanh
            float s6 = sp + sigm(a1[i]) * (fmaxf(p1[i], 0.f) - sp);  // step5: relu
            mean[i] += s5 + s6;
          }
        }
      }
    }
    if (sel == 0) wave_signal(chC + jb * 16, ep);  // covers s3,s4 agent stores + scr_s4 LDS
    // ---------- stage D: sel0: s7 from s3 ; sel1: s8 from s4 ; h = mean/8 ----------
    wave_wait(chC, ep);
    frag_load(af, sh + (size_t)(3 + sel) * 32768, rowoff);
    {
      f32x4 acc = mm(af, lw, 7 + sel, lane);
      float part[4];
#pragma unroll
      for (int i = 0; i < 4; ++i) part[i] = __shfl_xor(acc[i], 8);
      if (sel == 1) {
        if (n < 8) {
#pragma unroll
          for (int i = 0; i < 4; ++i) {
            float sp = scr_s4[sbase + i * 8];
            float s8 = sp + sigm(acc[i]) * (part[i] - sp);           // step7: identity
            scr_m1[sbase + i * 8] = mean[i] + s8;
          }
        }
        asm volatile("s_waitcnt lgkmcnt(0)" ::: "memory");
        if (lane == 0)
          __hip_atomic_store(&lflag[mt], ep, __ATOMIC_RELAXED, __HIP_MEMORY_SCOPE_WORKGROUP);
        // sel1 done for this t; loops back to its B-wait for t+1
      } else {
        while (__hip_atomic_load(&lflag[mt], __ATOMIC_RELAXED,
                                 __HIP_MEMORY_SCOPE_WORKGROUP) < ep) {}
        asm volatile("" ::: "memory");
        if (n < 8) {
#pragma unroll
          for (int i = 0; i < 4; ++i) {
            int m = rb + mt * 16 + r0 + i;
            float s7 = s3r[i] + sigm(acc[i]) * (sigm(part[i]) - s3r[i]);  // step6: sigmoid
            float hn = (mean[i] + s7 + scr_m1[sbase + i * 8]) * 0.125f;
            h_reg[i] = hn;
            sth(hh + m * 512 + jj, f2h(hn));
            out[((size_t)t * 64 + m) * 512 + jj] = hn;
            if (t == T_STEPS - 1) out[(size_t)T_STEPS * 64 * 512 + m * 512 + jj] = hn;
          }
        }
        wave_signal(chD + jb * 16, ep);
      }
    }
  }
}

extern "C" void kernel_launch(void* const* d_in, const int* in_sizes, int n_in,
                              void* d_out, int out_size, void* d_ws, size_t ws_size,
                              hipStream_t stream) {
  const float* x_in = (const float*)d_in[0];  // [512,64,512] f32
  const float* h_in = (const float*)d_in[1];  // [1,64,512]  f32
  const float* w0   = (const float*)d_in[2];  // [1024,1024] f32
  const float* wsrc = (const float*)d_in[3];  // [8,512,1024] f32
  float* out = (float*)d_out;
  char* ws = (char*)d_ws;

  const size_t O_BAR = 0;                       // 96 KB flag region (2 groups x 40 KB)
  const size_t O_WP  = 98304;                   // 10 MB packed fp16 weights
  const size_t O_XWP = O_WP + 10485760;         // 64 MB packed XW (u64 frags)
  const size_t O_SH  = O_XWP + 67108864;        // s0..s4 fp16: 5 x 65536 B
  const size_t O_HH  = O_SH + 327680;           // h fp16
  const size_t NEED  = O_HH + 65536;            // ~74.5 MB
  if (ws_size < NEED) return;

  u32* bar = (u32*)(ws + O_BAR);
  u16* wp  = (u16*)(ws + O_WP);
  u64* xwp = (u64*)(ws + O_XWP);
  u16* sh  = (u16*)(ws + O_SH);
  u16* hh  = (u16*)(ws + O_HH);

  const int LDS_BYTES = 151552;  // 147456 weights + scr + lds flags
  hipFuncSetAttribute((const void*)recur_kernel,
                      hipFuncAttributeMaxDynamicSharedMemorySize, LDS_BYTES);

  hipMemsetAsync(bar, 0, 98304, stream);  // zero all flag channels every call
  pack_kernel<<<dim3(2560), dim3(256), 0, stream>>>(w0, wsrc, wp);
  xw_kernel<<<dim3(8192), dim3(256), 0, stream>>>(x_in, wp, xwp);
  init_hh<<<dim3(128), dim3(256), 0, stream>>>(h_in, hh);
  recur_kernel<<<dim3(128), dim3(256), LDS_BYTES, stream>>>(xwp, h_in, wp, sh, hh, bar, out);
}